// Round 8
// baseline (84.413 us; speedup 1.0000x reference)
//
#include <hip/hip_runtime.h>

// ---------------------------------------------------------------------------
// Conv2dfft == 3x3 SAME cross-correlation conv (pad=1) + bias.
// N=32, C=128, F=128, H=W=32.  Implicit-GEMM, bf16 MFMA 16x16x32.
// Round 15: f-half blocks, GRID DECOMPOSITION FIXED. R13/R14 crashed (pytest
// abort, 2x container kills) because n_img=b>>3 ran 0..63 and h0=((b>>1)&3)
// only covered rows 0..15: OOB x reads and OOB out writes. Correct:
// 32 images x 8 htiles(4 rows) x 2 fhalves = 512 blocks:
//   n_img = b>>4, h0 = ((b>>1)&7)<<2, fhalf = b&1.
// Structure = R11's proven plain-__syncthreads pipeline (counted-vmcnt and
// setprio removed -- R12 measured them perf-null). Each block DMAs only its
// f-half's weight groups (12.3 KB/group; grid weight traffic 151 -> 75 MB),
// attacking the same-address L2 hot-line stream that R2/R3 identified as
// conv_main's dominant marginal cost.
// Wave = 1 output row x 64 f x 32 cols (s_row=wv), acc 4x2, 24 MFMA/phase,
// 12 phases; accumulation order IDENTICAL to R11 (bit-exact absmax).
// bc2 layout: [fhalf(2)][group(12)][q(3)][fblk4(4)][lane(64)][8 shorts].
// ---------------------------------------------------------------------------

typedef short bf16x8 __attribute__((ext_vector_type(8)));   // 8 bf16 (4 VGPR)
typedef short bf16x4 __attribute__((ext_vector_type(4)));   // 4 bf16 (2 VGPR)
typedef float f32x4  __attribute__((ext_vector_type(4)));   // MFMA 16x16 acc

__device__ __forceinline__ short f2bf(float f) {            // RNE fp32->bf16
  unsigned u = __builtin_bit_cast(unsigned, f);
  u = (u + 0x7fffu + ((u >> 16) & 1u)) >> 16;
  return (short)u;
}

// global -> LDS async DMA, 16B per lane. LDS dest = wave-uniform base +
// lane*16 (HW-applied); global src is per-lane.
__device__ __forceinline__ void gload_lds16(const void* g, void* l) {
  using gptr_t = const __attribute__((address_space(1))) unsigned int*;
  using lptr_t = __attribute__((address_space(3))) unsigned int*;
  __builtin_amdgcn_global_load_lds((gptr_t)(unsigned long long)g,
                                   (lptr_t)(unsigned int)(unsigned long long)l,
                                   16, 0, 0);
}

// ---------------------------------------------------------------------------
// Prepass: weight (F,C,3,3) fp32 -> bf16 fragment-major, f-half major:
//   bc2[fhalf(2)][grp(12)][q(3)][fblk4(4)][lane(64)][j(8)]
// A-frag elem j of lane (quad*16+l15) = W[f=fhalf*64+fblk4*16+l15]
//                                        [c=chunk*32+quad*8+j], grp=chunk*3+p,
// tap index = p*3+q. Per (fhalf,grp): 12,288 B contiguous (lane-linear).
// ---------------------------------------------------------------------------
__global__ __launch_bounds__(256) void conv_wprep(const float* __restrict__ w,
                                                  short* __restrict__ bc2) {
  int tid = blockIdx.x * 256 + threadIdx.x;    // [0, 147456)
  float v = w[tid];                            // coalesced
  int f   = tid / 1152;                        // w layout: f*1152 + c*9 + tap
  int rem = tid - f * 1152;
  int c   = rem / 9;
  int tap = rem - c * 9;
  int p = tap / 3, q = tap - p * 3;
  int grp   = (c >> 5) * 3 + p;                // chunk*3 + p
  int fhalf = f >> 6;
  int fblk4 = (f >> 4) & 3;
  int lane  = ((c >> 3) & 3) * 16 + (f & 15);  // quad*16 + l15
  int dst = ((((fhalf * 12 + grp) * 3 + q) * 4 + fblk4) * 512) + lane * 8 + (c & 7);
  bc2[dst] = f2bf(v);
}

// ---------------------------------------------------------------------------
// Main: 512 blocks (2/CU) x 256 threads (4 waves).
// Block b: n_img=b>>4, htile=(b>>1)&7 (rows h0=htile*4 .. +3), fhalf=b&1.
// Wave wv = output row s_row; 4x2 acc of 16x16 tiles (64 f x 32 cols).
// ---------------------------------------------------------------------------
__global__ __launch_bounds__(256, 2) void conv_main(
    const float* __restrict__ x, const short* __restrict__ bc2,
    const float* __restrict__ bias, float* __restrict__ out) {
  // xs[buf][row(6)][col(34)][c(32 + 8 pad)] ; stride 40 shorts = 80 B.
  __shared__ __align__(16) short xs[2][6 * 34 * 40];      // 32,640 B
  // afl[buf][q(3)][fblk4(4)][lane(64)][8 shorts] = 12,288 B per buffer.
  __shared__ __align__(16) short afl[2][6144];            // 24,576 B

  const int t    = threadIdx.x;
  const int lane = t & 63;
  const int wv   = t >> 6;
  const int b     = blockIdx.x;
  const int n_img = b >> 4;                    // [0,32)
  const int h0    = ((b >> 1) & 7) << 2;       // {0,4,...,28}
  const int fhalf = b & 1;

  const int l15   = lane & 15;
  const int quad  = lane >> 4;
  const int f_off = fhalf * 64;
  const int s_row = wv;            // this wave's output row within the tile

  const int w_ = t & 31;           // staged output col (coalesced)
  const int g  = t >> 5;           // staging group [0,8)
  const float* xb = x + n_img * 128 * 1024;

  // Per-lane global src base for af DMA (12,288 B per group, lane-linear).
  const char* bc2b = (const char*)bc2 + fhalf * 147456 + t * 16;

  // ---- stage af group 0 (3 x 16B DMA per thread, whole block = 12,288 B) ----
  {
    char* dst = (char*)&afl[0][0] + wv * 1024;   // wave-uniform; HW adds lane*16
#pragma unroll
    for (int r = 0; r < 3; ++r)
      gload_lds16(bc2b + r * 4096, dst + r * 4096);
  }

  // Zero halo cols (col 0 == w=-1, col 33 == w=32) in BOTH buffers, once.
  // 2 buf x 6 r x 2 col x 8 int2 = 192 threads.
  if (t < 192) {
    int buf = t / 96, rem = t % 96;
    int r = rem >> 4, rem2 = rem & 15;
    int colsel = rem2 >> 3, q4 = rem2 & 7;
    *(int2*)&xs[buf][(r * 34 + colsel * 33) * 40 + q4 * 4] = make_int2(0, 0);
  }

  f32x4 acc[4][2] = {};            // [mt(f)][nt(col-half)]
  float xv[24];

  // ---- chunk 0 x -> regs -> buf 0 : rows h0-1..h0+4, 32 c ----
#pragma unroll
  for (int i = 0; i < 6; ++i) {
    int idx = i * 8 + g;           // [0,48) = r*8 + cq
    int r = idx >> 3, cq = idx & 7;
    int hr = h0 - 1 + r;
    bool ok = (unsigned)hr < 32u;
#pragma unroll
    for (int cc = 0; cc < 4; ++cc)
      xv[i * 4 + cc] = ok ? xb[(cq * 4 + cc) * 1024 + hr * 32 + w_] : 0.f;
  }
#pragma unroll
  for (int i = 0; i < 6; ++i) {
    int idx = i * 8 + g;
    int r = idx >> 3, cq = idx & 7;
    bf16x4 v = { f2bf(xv[i*4+0]), f2bf(xv[i*4+1]), f2bf(xv[i*4+2]), f2bf(xv[i*4+3]) };
    *(bf16x4*)&xs[0][(r * 34 + w_ + 1) * 40 + cq * 4] = v;
  }
  __syncthreads();                 // prologue: af grp-0 DMA + x0 staged

#pragma unroll
  for (int chunk = 0; chunk < 4; ++chunk) {
#pragma unroll
    for (int p = 0; p < 3; ++p) {
      const int grp = chunk * 3 + p;
      // ---- issue next group's af DMA (drained by this phase's end barrier) ----
      if (grp < 11) {
        const char* src = bc2b + (grp + 1) * 12288;
        char* dst = (char*)&afl[(grp + 1) & 1][0] + wv * 1024;
#pragma unroll
        for (int r = 0; r < 3; ++r)
          gload_lds16(src + r * 4096, dst + r * 4096);
      }
      // ---- issue next chunk's x loads at p==1 (consumed at p==2 ds_write) ----
      if (p == 1 && chunk < 3) {
#pragma unroll
        for (int i = 0; i < 6; ++i) {
          int idx = i * 8 + g;
          int r = idx >> 3, cq = idx & 7;
          int hr = h0 - 1 + r;
          bool ok = (unsigned)hr < 32u;
#pragma unroll
          for (int cc = 0; cc < 4; ++cc)
            xv[i * 4 + cc] =
                ok ? xb[((chunk + 1) * 32 + cq * 4 + cc) * 1024 + hr * 32 + w_] : 0.f;
        }
      }
      // ---- compute phase: af from LDS, x from LDS, 24 MFMA ----
      const short* xbuf = xs[chunk & 1];
      const short* afb  = afl[grp & 1];
      bf16x8 af[12];
#pragma unroll
      for (int q = 0; q < 3; ++q)
#pragma unroll
        for (int mt = 0; mt < 4; ++mt)
          af[q * 4 + mt] = *(const bf16x8*)&afb[(q * 4 + mt) * 512 + lane * 8];
#pragma unroll
      for (int q = 0; q < 3; ++q) {
        bf16x8 bfr[2];
#pragma unroll
        for (int nt = 0; nt < 2; ++nt) {
          int r   = s_row + p;
          int col = nt * 16 + l15 + q;
          bfr[nt] = *(const bf16x8*)&xbuf[(r * 34 + col) * 40 + quad * 8];
        }
#pragma unroll
        for (int mt = 0; mt < 4; ++mt)
#pragma unroll
          for (int nt = 0; nt < 2; ++nt)
            acc[mt][nt] = __builtin_amdgcn_mfma_f32_16x16x32_bf16(
                af[q * 4 + mt], bfr[nt], acc[mt][nt], 0, 0, 0);
      }
      // ---- stage prefetched x into the other buffer (p==2) ----
      if (p == 2 && chunk < 3) {
#pragma unroll
        for (int i = 0; i < 6; ++i) {
          int idx = i * 8 + g;
          int r = idx >> 3, cq = idx & 7;
          bf16x4 v = { f2bf(xv[i*4+0]), f2bf(xv[i*4+1]), f2bf(xv[i*4+2]), f2bf(xv[i*4+3]) };
          *(bf16x4*)&xs[(chunk + 1) & 1][(r * 34 + w_ + 1) * 40 + cq * 4] = v;
        }
      }
      if (grp < 11) __syncthreads();   // af buffer swap + DMA drain
    }
  }

  // ---- epilogue: C/D layout col=lane&15 (w), row=quad*4+reg (f) ----
  const int h = h0 + s_row;
#pragma unroll
  for (int nt = 0; nt < 2; ++nt) {
    int w_out = nt * 16 + l15;
#pragma unroll
    for (int mt = 0; mt < 4; ++mt) {
#pragma unroll
      for (int reg = 0; reg < 4; ++reg) {
        int f = f_off + mt * 16 + quad * 4 + reg;
        out[(((size_t)n_img * 128 + f) * 32 + h) * 32 + w_out] =
            acc[mt][nt][reg] + bias[f];
      }
    }
  }
}

// ---------------------------------------------------------------------------
extern "C" void kernel_launch(void* const* d_in, const int* in_sizes, int n_in,
                              void* d_out, int out_size, void* d_ws, size_t ws_size,
                              hipStream_t stream) {
  const float* x    = (const float*)d_in[0];   // 32*128*32*32
  const float* w    = (const float*)d_in[1];   // 128*128*3*3
  const float* bias = (const float*)d_in[2];   // 128
  float* out = (float*)d_out;                  // 32*128*32*32
  short* bc2 = (short*)d_ws;                   // 294,912 B fragment-major weights

  conv_wprep<<<576, 256, 0, stream>>>(w, bc2);
  conv_main<<<512, 256, 0, stream>>>(x, bc2, bias, out);
}